// Round 7
// baseline (282.124 us; speedup 1.0000x reference)
//
#include <hip/hip_runtime.h>
#include <hip/hip_bf16.h>

#define BB 64
#define TT 2048
#define DD 256
#define EPSF 1e-7f
#define PADS 272   // shorts per padded LDS row = 544 B = 34*16B -> perfectly uniform bank spread

typedef __attribute__((ext_vector_type(8))) short v8s;   // 8 x bf16 (4 VGPRs) — MFMA A/B frag
typedef __attribute__((ext_vector_type(4))) float v4f;   // MFMA C/D frag

__device__ __forceinline__ float bf2f(unsigned short u) {
    union { unsigned int i; float f; } c;
    c.i = ((unsigned int)u) << 16;
    return c.f;
}

__device__ __forceinline__ unsigned int pack2_bf16(float a, float b) {
    union { __hip_bfloat162 h; unsigned int u; } c;
    c.h = __float22bfloat162_rn(make_float2(a, b));   // v_cvt_pk_bf16_f32, RNE
    return c.u;
}

// exact identity tanh(x) = 1 - 2/(exp(2x)+1)
__device__ __forceinline__ float tanh_fast(float x) {
    float e = __expf(2.0f * x);
    return 1.0f - 2.0f / (e + 1.0f);
}

// ---------------- kernel 1: W[d][e] (fp32) -> Wt[e][d] (bf16), LDS tile transpose ----------------
__global__ __launch_bounds__(256) void pack_wt(const float* __restrict__ W,
                                               unsigned short* __restrict__ Wt) {
    __shared__ float tile[32][33];
    int bx = blockIdx.x & 7;    // d-tile
    int by = blockIdx.x >> 3;   // e-tile
    int r  = threadIdx.x >> 3;        // 0..31
    int c4 = (threadIdx.x & 7) * 4;   // 0,4,...,28
    float4 v = *(const float4*)(W + (size_t)(bx * 32 + r) * DD + by * 32 + c4);
    tile[r][c4 + 0] = v.x; tile[r][c4 + 1] = v.y;
    tile[r][c4 + 2] = v.z; tile[r][c4 + 3] = v.w;
    __syncthreads();
    float a0 = tile[c4 + 0][r], a1 = tile[c4 + 1][r];
    float a2 = tile[c4 + 2][r], a3 = tile[c4 + 3][r];
    uint2 pp = make_uint2(pack2_bf16(a0, a1), pack2_bf16(a2, a3));
    *(uint2*)(Wt + (size_t)(by * 32 + r) * DD + bx * 32 + c4) = pp;
}

// ---------------- kernel 2: fused; B temporal through LDS, reg-prefetched -----------------------
// Block = 2 waves x 32 rows. x wave-private in LDS (read for A-frags AND epilogue).
// A-frags cached in regs (64 VGPR). 8 j-steps, each = 32 n-columns: B-slice (16 KB) staged in
// LDS (shared), next slice register-prefetched during compute. esum accumulates all n in-wave.
__global__ __launch_bounds__(128, 2) void fused_att4(const float* __restrict__ x,
                                                     const unsigned short* __restrict__ Wt,
                                                     const float* __restrict__ bias,
                                                     const float* __restrict__ uw,
                                                     const int* __restrict__ mask,
                                                     float* __restrict__ numpart,
                                                     float* __restrict__ denpart) {
    __shared__ __align__(16) unsigned short xbuf[64 * PADS];   // 34816 B
    __shared__ __align__(16) unsigned short bbuf[32 * PADS];   // 17408 B (re-aliased as merge buf)

    const int tid  = threadIdx.x;
    const int w    = tid >> 6;     // wave 0..1
    const int lane = tid & 63;
    const int q    = lane >> 4;    // 0..3
    const int m    = lane & 15;    // 0..15
    const long RW  = (long)blockIdx.x * 64 + w * 32;   // this wave's 32 rows

    // ---- stage x: wave-private rows; 1 coalesced dwordx4 per row, conflict-free ds_write_b64
    {
        const float* gp = x + RW * DD + lane * 4;
        unsigned short* sp = xbuf + (size_t)(w * 32) * PADS + lane * 4;
#pragma unroll 8
        for (int r = 0; r < 32; ++r) {
            float4 v = *(const float4*)(gp + (size_t)r * DD);
            uint2 pp = make_uint2(pack2_bf16(v.x, v.y), pack2_bf16(v.z, v.w));
            *(uint2*)(sp + (size_t)r * PADS) = pp;
        }
    }
    // no barrier: xbuf slice is only ever touched by this wave

    // ---- A fragments, register-cached for the whole kernel: A[m][k=q*8+j]
    v8s A[2][8];
#pragma unroll
    for (int mt = 0; mt < 2; ++mt) {
        const unsigned short* ap = xbuf + (size_t)(w * 32 + mt * 16 + m) * PADS + q * 8;
#pragma unroll
        for (int ks = 0; ks < 8; ++ks) A[mt][ks] = *(const v8s*)(ap + ks * 32);
    }

    // ---- register-prefetch B slice 0 (each wave stages 16 of the 32 Wt rows)
    const int nloc = w * 16 + (lane >> 5);   // LDS row this lane writes (per it: +2)
    const int c8   = (lane & 31) * 8;        // shorts offset within row (16 B per lane)
    uint4 breg[8];
    {
        const unsigned short* gB = Wt + (size_t)nloc * DD + c8;
#pragma unroll
        for (int it = 0; it < 8; ++it) breg[it] = *(const uint4*)(gB + (size_t)(it * 2) * DD);
    }

    float esum[2][4] = {{0.f, 0.f, 0.f, 0.f}, {0.f, 0.f, 0.f, 0.f}};

    for (int j = 0; j < 8; ++j) {
        __syncthreads();   // both waves done reading previous bbuf contents
        {
            unsigned short* sb = bbuf + (size_t)nloc * PADS + c8;
#pragma unroll
            for (int it = 0; it < 8; ++it)
                *(uint4*)(sb + (size_t)(it * 2) * PADS) = breg[it];
        }
        if (j < 7) {   // prefetch next slice; latency hidden under this j's compute
            const unsigned short* gB = Wt + (size_t)((j + 1) * 32 + nloc) * DD + c8;
#pragma unroll
            for (int it = 0; it < 8; ++it)
                breg[it] = *(const uint4*)(gB + (size_t)(it * 2) * DD);
        }
        __syncthreads();   // bbuf ready

        float b_r[2], u_r[2];
#pragma unroll
        for (int ntl = 0; ntl < 2; ++ntl) {
            int n = j * 32 + ntl * 16 + m;
            b_r[ntl] = bias[n];
            u_r[ntl] = uw[n];
        }
#pragma unroll
        for (int ntl = 0; ntl < 2; ++ntl) {
            const unsigned short* bp = bbuf + (size_t)(ntl * 16 + m) * PADS + q * 8;
            v8s B0[8];
#pragma unroll
            for (int ks = 0; ks < 8; ++ks) B0[ks] = *(const v8s*)(bp + ks * 32);
            v4f a0 = {0.f, 0.f, 0.f, 0.f};
            v4f a1 = {0.f, 0.f, 0.f, 0.f};
#pragma unroll
            for (int ks = 0; ks < 8; ++ks) {
                a0 = __builtin_amdgcn_mfma_f32_16x16x32_bf16(A[0][ks], B0[ks], a0, 0, 0, 0);
                a1 = __builtin_amdgcn_mfma_f32_16x16x32_bf16(A[1][ks], B0[ks], a1, 0, 0, 0);
            }
#pragma unroll
            for (int r = 0; r < 4; ++r) {
                esum[0][r] += tanh_fast(a0[r] + b_r[ntl]) * u_r[ntl];
                esum[1][r] += tanh_fast(a1[r] + b_r[ntl]) * u_r[ntl];
            }
        }
    }
    __syncthreads();   // last B reads done -> bbuf may be re-aliased as merge buffer

    // ---- reduce e over the 16 n-lanes (stays within each 16-lane group)
#pragma unroll
    for (int o = 1; o < 16; o <<= 1)
#pragma unroll
        for (int mt = 0; mt < 2; ++mt)
#pragma unroll
            for (int r = 0; r < 4; ++r)
                esum[mt][r] += __shfl_xor(esum[mt][r], o, 64);

    // ---- p = exp(e)*mask for this lane's 8 rows (rows mt*16 + q*4 + r)
    float p_loc[2][4];
#pragma unroll
    for (int mt = 0; mt < 2; ++mt) {
        const int4 mv = *(const int4*)(mask + RW + mt * 16 + q * 4);
        p_loc[mt][0] = __expf(esum[mt][0]) * (float)mv.x;
        p_loc[mt][1] = __expf(esum[mt][1]) * (float)mv.y;
        p_loc[mt][2] = __expf(esum[mt][2]) * (float)mv.z;
        p_loc[mt][3] = __expf(esum[mt][3]) * (float)mv.w;
    }

    // ---- gather p for all 32 rows of this wave; den = sum
    float p_all[32];
    float den = 0.f;
#pragma unroll
    for (int i = 0; i < 32; ++i) {
        p_all[i] = __shfl(p_loc[i >> 4][i & 3], ((i >> 2) & 3) * 16 + m, 64);
        den += p_all[i];
    }

    // ---- weighted sum over own 32 rows from own xbuf slice; lane covers d = lane*4..+3
    float num[4] = {0.f, 0.f, 0.f, 0.f};
    {
        const unsigned short* xp = xbuf + (size_t)(w * 32) * PADS + lane * 4;
#pragma unroll 8
        for (int t = 0; t < 32; ++t) {
            uint2 xv = *(const uint2*)(xp + (size_t)t * PADS);
            float pt = p_all[t];
            num[0] += pt * bf2f((unsigned short)(xv.x & 0xffffu));
            num[1] += pt * bf2f((unsigned short)(xv.x >> 16));
            num[2] += pt * bf2f((unsigned short)(xv.y & 0xffffu));
            num[3] += pt * bf2f((unsigned short)(xv.y >> 16));
        }
    }

    // ---- merge 2 wave-partials via bbuf-aliased buffer, store per-block partials
    float* red = (float*)bbuf;   // 514 floats used of 17408 B
    *(float4*)&red[w * 256 + lane * 4] = make_float4(num[0], num[1], num[2], num[3]);
    if (lane == 0) red[512 + w] = den;
    __syncthreads();
    numpart[(size_t)blockIdx.x * DD + tid]       = red[tid] + red[256 + tid];
    numpart[(size_t)blockIdx.x * DD + 128 + tid] = red[128 + tid] + red[384 + tid];
    if (tid == 0) denpart[blockIdx.x] = red[512] + red[513];
}

// ---------------- kernel 3: out[b][d] = sum_c num[b*32+c][d] / (sum_c den[b*32+c] + EPS) ------
__global__ __launch_bounds__(256) void finalize(const float* __restrict__ numpart,
                                                const float* __restrict__ denpart,
                                                float* __restrict__ out) {
    __shared__ float dsh;
    int b = blockIdx.x, d = threadIdx.x;
    if (d == 0) {
        float s = 0.f;
        for (int c = 0; c < 32; ++c) s += denpart[b * 32 + c];
        dsh = s + EPSF;
    }
    __syncthreads();
    float s = 0.f;
#pragma unroll
    for (int c = 0; c < 32; ++c) s += numpart[(size_t)(b * 32 + c) * DD + d];
    out[(size_t)b * DD + d] = s / dsh;
}

extern "C" void kernel_launch(void* const* d_in, const int* in_sizes, int n_in,
                              void* d_out, int out_size, void* d_ws, size_t ws_size,
                              hipStream_t stream) {
    const float* x    = (const float*)d_in[0];  // [64,2048,256] fp32 (bf16-rounded values)
    const float* W    = (const float*)d_in[1];  // [256,256] fp32
    const float* bias = (const float*)d_in[2];  // [256] fp32
    const float* uw   = (const float*)d_in[3];  // [256] fp32
    const int*   mask = (const int*)d_in[4];    // [64,2048] int32
    float*       out  = (float*)d_out;          // [64,256] fp32

    char* ws = (char*)d_ws;
    unsigned short* Wt = (unsigned short*)ws;             // 128 KB bf16 W^T
    float* numpart     = (float*)(ws + 131072);           // 2 MB
    float* denpart     = (float*)(ws + 131072 + 2097152); // 8 KB

    pack_wt<<<dim3(64), dim3(256), 0, stream>>>(W, Wt);
    fused_att4<<<dim3(2048), dim3(128), 0, stream>>>(x, Wt, bias, uw, mask, numpart, denpart);
    finalize<<<dim3(64), dim3(256), 0, stream>>>(numpart, denpart, out);
}